// Round 5
// baseline (1132.253 us; speedup 1.0000x reference)
//
#include <hip/hip_runtime.h>

typedef __attribute__((ext_vector_type(4))) float f32x4;
typedef __attribute__((ext_vector_type(8))) _Float16 f16x8;

#define AS1 __attribute__((address_space(1)))
#define AS3 __attribute__((address_space(3)))

// async global->LDS, 16B per lane (dest = wave-uniform base + lane*16B)
__device__ __forceinline__ void async16(const void* g, void* l) {
  __builtin_amdgcn_global_load_lds((const AS1 void*)g, (AS3 void*)l, 16, 0, 0);
}

// Uniform cubic B-spline bases, closed form. Extended grid knots t_j =
// (j-3)*0.4f - 1.0f (j=0..11) are uniformly spaced, so for x in cell c
// (= [t_c, t_c+0.4)) only splines j=c-3..c are nonzero, with the cardinal
// cubic weights. C2 continuity makes ulp-level cell misassignment at knot
// boundaries harmless (weights agree at the boundary).
__device__ __forceinline__ f16x8 expand_bases(float x) {
  const float t0 = (float)(-3) * 0.4f - 1.0f;
  float s = (x - t0) * 2.5f;
  bool in = (s >= 0.0f) && (s < 11.0f);
  int c = (int)s;
  c = c > 10 ? 10 : c;
  float u = s - (float)c;
  float um = 1.0f - u;
  float u2 = u * u, u3 = u2 * u;
  float w3 = in ? u3 * (1.0f / 6.0f) : 0.f;                                // j = c   (rising tail)
  float w2 = in ? (1.0f + 3.0f * u + 3.0f * u2 - 3.0f * u3) * (1.0f / 6.0f) : 0.f;  // j = c-1
  float w1 = in ? (4.0f - 6.0f * u2 + 3.0f * u3) * (1.0f / 6.0f) : 0.f;    // j = c-2
  float w0 = in ? um * um * um * (1.0f / 6.0f) : 0.f;                      // j = c-3 (falling tail)
  f16x8 r;
#pragma unroll
  for (int j = 0; j < 8; ++j) {
    int d = c - j;
    float w = (d == 0) ? w3 : (d == 1) ? w2 : (d == 2) ? w1 : (d == 3) ? w0 : 0.f;
    r[j] = (_Float16)w;
  }
  return r;
}

// gate_probs[b][e] = softmax_e( x[b,:] . gate_w[e,:] + gate_b[e] ), fp32
__global__ __launch_bounds__(256) void gate_kernel(const float* __restrict__ x,
                                                   const float* __restrict__ gw,
                                                   const float* __restrict__ gb,
                                                   float* __restrict__ gate) {
  const int b = blockIdx.x * 4 + (threadIdx.x >> 6);
  const int lane = threadIdx.x & 63;
  f32x4 x0 = *(const f32x4*)(x + ((size_t)b << 9) + lane * 8);
  f32x4 x1 = *(const f32x4*)(x + ((size_t)b << 9) + lane * 8 + 4);
  float lg[8];
#pragma unroll
  for (int e = 0; e < 8; ++e) {
    f32x4 w0 = *(const f32x4*)(gw + ((size_t)e << 9) + lane * 8);
    f32x4 w1 = *(const f32x4*)(gw + ((size_t)e << 9) + lane * 8 + 4);
    float d = 0.f;
#pragma unroll
    for (int j = 0; j < 4; ++j) d += x0[j] * w0[j] + x1[j] * w1[j];
#pragma unroll
    for (int m = 32; m >= 1; m >>= 1) d += __shfl_xor(d, m, 64);
    lg[e] = d + gb[e];
  }
  float mx = lg[0];
#pragma unroll
  for (int e = 1; e < 8; ++e) mx = fmaxf(mx, lg[e]);
  float p[8], ssum = 0.f;
#pragma unroll
  for (int e = 0; e < 8; ++e) { p[e] = __expf(lg[e] - mx); ssum += p[e]; }
  float mine = 0.f;
#pragma unroll
  for (int e = 0; e < 8; ++e) mine = (lane == e) ? p[e] / ssum : mine;
  if (lane < 8) gate[(size_t)b * 8 + lane] = mine;
}

// W'[row][k] (row = e*512+o, ld=4608), fp16: k<512 -> base_w[row][k];
// k>=512 -> spline_w[row][i][c]*scaler[row][i] at k = 512 + i*8 + c.
__global__ __launch_bounds__(256) void prep_w_kernel(const float* __restrict__ bw,
                                                     const float* __restrict__ sw,
                                                     const float* __restrict__ sc,
                                                     _Float16* __restrict__ W) {
  size_t tid = (size_t)blockIdx.x * 256 + threadIdx.x;
  const size_t NSPL = (size_t)4096 * 512;
  if (tid < NSPL) {
    size_t row = tid >> 9;
    int i = (int)(tid & 511);
    float s = sc[(row << 9) + i];
    const float* sp = sw + (((row << 9) + (size_t)i) << 3);
    f32x4 v0 = *(const f32x4*)sp;
    f32x4 v1 = *(const f32x4*)(sp + 4);
    f16x8 o;
#pragma unroll
    for (int j = 0; j < 4; ++j) { o[j] = (_Float16)(v0[j] * s); o[4 + j] = (_Float16)(v1[j] * s); }
    *(f16x8*)(W + row * 4608 + 512 + (size_t)i * 8) = o;
  } else {
    size_t t2 = tid - NSPL;  // < 4096*64
    size_t row = t2 >> 6;
    int i8 = (int)((t2 & 63) << 3);
    const float* bp = bw + (row << 9) + i8;
    f32x4 v0 = *(const f32x4*)bp;
    f32x4 v1 = *(const f32x4*)(bp + 4);
    f16x8 o;
#pragma unroll
    for (int j = 0; j < 4; ++j) { o[j] = (_Float16)v0[j]; o[4 + j] = (_Float16)v1[j]; }
    *(f16x8*)(W + row * 4608 + i8) = o;
  }
}

// A1[r][k] fp16, full M: k<512 silu(x), else bases(x_i)[c]
__global__ __launch_bounds__(256) void expand_x_kernel(const float* __restrict__ x,
                                                       _Float16* __restrict__ A1) {
  const int tid = blockIdx.x * 256 + threadIdx.x;
  const int r = tid >> 9;
  const int i = tid & 511;
  const float xv = x[((size_t)r << 9) + i];
  const float s = xv / (1.0f + __expf(-xv));
  _Float16* drow = A1 + (size_t)r * 4608;
  drow[i] = (_Float16)s;
  *(f16x8*)(drow + 512 + (size_t)i * 8) = expand_bases(xv);
}

// Layer-1 GEMM: 128x128 tile, K=4608, BK=32, async staging both operands
// (m97 structure). Epilogue writes h fp16 [e][4096][512] (no expansion).
__global__ __launch_bounds__(256) void gemm_h(const _Float16* __restrict__ A1,
                                              const _Float16* __restrict__ W1,
                                              _Float16* __restrict__ h) {
  __shared__ _Float16 As[128 * 32];
  __shared__ _Float16 Bs[128 * 32];
  const int t = threadIdx.x;
  const int e = blockIdx.z;
  const int tileM = blockIdx.x * 128;
  const int tileN = blockIdx.y * 128;
  const _Float16* B = W1 + (size_t)e * 512 * 4608;

  const int srow = t >> 2;
  const int scol = (t & 3) * 8;
  const _Float16* gA0 = A1 + (size_t)(tileM + srow) * 4608 + scol;
  const _Float16* gA1 = A1 + (size_t)(tileM + 64 + srow) * 4608 + scol;
  const _Float16* gB0 = B + (size_t)(tileN + srow) * 4608 + scol;
  const _Float16* gB1 = B + (size_t)(tileN + 64 + srow) * 4608 + scol;
  _Float16* lA0 = &As[t * 8];
  _Float16* lA1 = &As[2048 + t * 8];
  _Float16* lB0 = &Bs[t * 8];
  _Float16* lB1 = &Bs[2048 + t * 8];

  const int lane = t & 63;
  const int wm = ((t >> 6) & 1) * 64;
  const int wn = ((t >> 6) >> 1) * 64;
  const int l16 = lane & 15;
  const int quad = lane >> 4;

  f32x4 acc[4][4];
#pragma unroll
  for (int i = 0; i < 4; ++i)
#pragma unroll
    for (int j = 0; j < 4; ++j) acc[i][j] = (f32x4){0.f, 0.f, 0.f, 0.f};

  for (int k0 = 0; k0 < 4608; k0 += 32) {
    async16(gA0 + k0, lA0);
    async16(gA1 + k0, lA1);
    async16(gB0 + k0, lB0);
    async16(gB1 + k0, lB1);
    __syncthreads();
    f16x8 af[4], bfr[4];
#pragma unroll
    for (int mt = 0; mt < 4; ++mt)
      af[mt] = *(const f16x8*)(&As[(wm + mt * 16 + l16) * 32 + quad * 8]);
#pragma unroll
    for (int nt = 0; nt < 4; ++nt)
      bfr[nt] = *(const f16x8*)(&Bs[(wn + nt * 16 + l16) * 32 + quad * 8]);
#pragma unroll
    for (int mt = 0; mt < 4; ++mt)
#pragma unroll
      for (int nt = 0; nt < 4; ++nt)
        acc[mt][nt] = __builtin_amdgcn_mfma_f32_16x16x32_f16(af[mt], bfr[nt], acc[mt][nt], 0, 0, 0);
    __syncthreads();
  }

  // C/D layout: col = lane&15, row = quad*4 + reg
  _Float16* hd = h + (size_t)e * 4096 * 512;
#pragma unroll
  for (int mt = 0; mt < 4; ++mt) {
#pragma unroll
    for (int r = 0; r < 4; ++r) {
      const int m = tileM + wm + mt * 16 + quad * 4 + r;
#pragma unroll
      for (int nt = 0; nt < 4; ++nt) {
        const int n = tileN + wn + nt * 16 + l16;
        hd[(size_t)m * 512 + n] = (_Float16)acc[mt][nt][r];
      }
    }
  }
}

// Layer-2 GEMM: A-operand built on the fly from h (silu for k<512, bases
// for k>=512); B = W2' async-staged. Epilogue: atomicAdd gate[b,e]*val.
__global__ __launch_bounds__(256) void gemm_out(const _Float16* __restrict__ h,
                                                const _Float16* __restrict__ W2,
                                                const float* __restrict__ gate,
                                                float* __restrict__ out) {
  __shared__ _Float16 As[128 * 32];
  __shared__ _Float16 Bs[128 * 32];
  const int t = threadIdx.x;
  const int e = blockIdx.z;
  const int tileM = blockIdx.x * 128;
  const int tileN = blockIdx.y * 128;
  const _Float16* hsrc = h + (size_t)e * 4096 * 512;
  const _Float16* B = W2 + (size_t)e * 512 * 4608;

  const int srow = t >> 2;
  const int scol = (t & 3) * 8;
  const _Float16* gB0 = B + (size_t)(tileN + srow) * 4608 + scol;
  const _Float16* gB1 = B + (size_t)(tileN + 64 + srow) * 4608 + scol;
  _Float16* lB0 = &Bs[t * 8];
  _Float16* lB1 = &Bs[2048 + t * 8];

  const int row = t >> 1;            // A-build: 2 threads per tile row
  const int half = t & 1;
  const _Float16* hrow = hsrc + (size_t)(tileM + row) * 512;

  const int lane = t & 63;
  const int wm = ((t >> 6) & 1) * 64;
  const int wn = ((t >> 6) >> 1) * 64;
  const int l16 = lane & 15;
  const int quad = lane >> 4;

  f32x4 acc[4][4];
#pragma unroll
  for (int i = 0; i < 4; ++i)
#pragma unroll
    for (int j = 0; j < 4; ++j) acc[i][j] = (f32x4){0.f, 0.f, 0.f, 0.f};

  for (int k0 = 0; k0 < 4608; k0 += 32) {
    async16(gB0 + k0, lB0);
    async16(gB1 + k0, lB1);
    if (k0 < 512) {
      // As[row][col] = silu(h[row][k0+col]); thread covers 16 cols
      const _Float16* hp = hrow + k0 + half * 16;
      f16x8 h0 = *(const f16x8*)hp;
      f16x8 h1 = *(const f16x8*)(hp + 8);
      f16x8 s0, s1;
#pragma unroll
      for (int j = 0; j < 8; ++j) {
        float v0 = (float)h0[j], v1 = (float)h1[j];
        s0[j] = (_Float16)(v0 / (1.0f + __expf(-v0)));
        s1[j] = (_Float16)(v1 / (1.0f + __expf(-v1)));
      }
      *(f16x8*)&As[row * 32 + half * 16] = s0;
      *(f16x8*)&As[row * 32 + half * 16 + 8] = s1;
    } else {
      // cols = (i-i0)*8 + c for i in i0..i0+3; thread covers 2 i's
      const int i0 = (k0 - 512) >> 3;
      const int ip = half * 2;
      const _Float16* hp = hrow + i0 + ip;
      float ha = (float)hp[0], hb = (float)hp[1];
      *(f16x8*)&As[row * 32 + ip * 8] = expand_bases(ha);
      *(f16x8*)&As[row * 32 + ip * 8 + 8] = expand_bases(hb);
    }
    __syncthreads();
    f16x8 af[4], bfr[4];
#pragma unroll
    for (int mt = 0; mt < 4; ++mt)
      af[mt] = *(const f16x8*)(&As[(wm + mt * 16 + l16) * 32 + quad * 8]);
#pragma unroll
    for (int nt = 0; nt < 4; ++nt)
      bfr[nt] = *(const f16x8*)(&Bs[(wn + nt * 16 + l16) * 32 + quad * 8]);
#pragma unroll
    for (int mt = 0; mt < 4; ++mt)
#pragma unroll
      for (int nt = 0; nt < 4; ++nt)
        acc[mt][nt] = __builtin_amdgcn_mfma_f32_16x16x32_f16(af[mt], bfr[nt], acc[mt][nt], 0, 0, 0);
    __syncthreads();
  }

#pragma unroll
  for (int mt = 0; mt < 4; ++mt) {
#pragma unroll
    for (int r = 0; r < 4; ++r) {
      const int m = tileM + wm + mt * 16 + quad * 4 + r;
      const float gp = gate[(size_t)m * 8 + e];
      float* orow = out + (size_t)m * 512;
#pragma unroll
      for (int nt = 0; nt < 4; ++nt) {
        const int n = tileN + wn + nt * 16 + l16;
        atomicAdd(orow + n, gp * acc[mt][nt][r]);
      }
    }
  }
}

extern "C" void kernel_launch(void* const* d_in, const int* in_sizes, int n_in,
                              void* d_out, int out_size, void* d_ws, size_t ws_size,
                              hipStream_t stream) {
  (void)in_sizes; (void)n_in; (void)out_size; (void)ws_size;
  const float* x   = (const float*)d_in[0];
  const float* gw  = (const float*)d_in[1];
  const float* gb  = (const float*)d_in[2];
  const float* bw1 = (const float*)d_in[3];
  const float* sw1 = (const float*)d_in[4];
  const float* sc1 = (const float*)d_in[5];
  const float* bw2 = (const float*)d_in[6];
  const float* sw2 = (const float*)d_in[7];
  const float* sc2 = (const float*)d_in[8];
  float* out = (float*)d_out;

  auto al = [](size_t v) { return (v + 255) & ~(size_t)255; };
  const size_t GATE_B = (size_t)4096 * 8 * 4;
  const size_t W_B    = (size_t)8 * 512 * 4608 * 2;   // 37.7 MB fp16
  const size_t A1_B   = (size_t)4096 * 4608 * 2;      // 37.7 MB fp16
  const size_t H_B    = (size_t)8 * 4096 * 512 * 2;   // 33.5 MB fp16
  // total ~222 MB; ws_size >= ~321 MB (round-3 evidence: Mc=2048 fit)

  char* p = (char*)d_ws;
  float* gate   = (float*)p; p += al(GATE_B);
  _Float16* W1  = (_Float16*)p; p += al(W_B);
  _Float16* W2  = (_Float16*)p; p += al(W_B);
  _Float16* A1  = (_Float16*)p; p += al(A1_B);
  _Float16* hbuf = (_Float16*)p;

  // harness poisons d_out with 0xAA before every timed launch — zero it
  hipMemsetAsync(out, 0, (size_t)4096 * 512 * 4, stream);
  gate_kernel<<<1024, 256, 0, stream>>>(x, gw, gb, gate);
  prep_w_kernel<<<9216, 256, 0, stream>>>(bw1, sw1, sc1, W1);
  prep_w_kernel<<<9216, 256, 0, stream>>>(bw2, sw2, sc2, W2);
  expand_x_kernel<<<8192, 256, 0, stream>>>(x, A1);

  dim3 grid(32, 4, 8);
  gemm_h<<<grid, 256, 0, stream>>>(A1, W1, hbuf);
  gemm_out<<<grid, 256, 0, stream>>>(hbuf, W2, gate, out);
}